// Round 14
// baseline (1765.794 us; speedup 1.0000x reference)
//
#include <hip/hip_runtime.h>
#include <cstdint>
#include <cmath>

// LSTM: B=64, T=2048, H=128, gates=4H=512. f32 throughout.
//
// Round 14: R13 fused ran but was slower than two-kernel (1824 vs 1676us).
// Diagnosis: consumer VALUBusy% unchanged but duration +39% -> the R13 loop
// EXECUTED ~39% more instructions (dual LDS/global xnn select, window test,
// tc*HID addressing, wait machinery -- all per-step). Fix: tight nested loops.
//   outer: 64 windows (flag-wait + base pointers ONCE per 32 steps)
//   inner: exact R10 step body, single xg source, running pointers,
//          #pragma unroll 1 (I-cache).
// Protocol unchanged (R13): producers cover windows 1..63 (252MB ring, fits
// ws); consumer self-computes window 0 into LDS; release/acquire AGENT flags.

#define HID 128
#define G4  512
#define BB  64
#define TT  2048

typedef float v2f __attribute__((ext_vector_type(2)));
typedef float v4f __attribute__((ext_vector_type(4)));

#define PIN2(v) asm volatile("" : "+v"(v))
#define FMA2(A, B, C) __builtin_elementwise_fma((A), (B), (C))
#define LOG2E  1.442695041f

template<int CTRL>
__device__ __forceinline__ float dpp_mov(float v) {
    return __int_as_float(__builtin_amdgcn_update_dpp(
        0, __float_as_int(v), CTRL, 0xF, 0xF, true));
}
// 8-lane butterfly sum (validated R5-R10).
#define BF8(p) { p += dpp_mov<0xB1>(p); p += dpp_mov<0x4E>(p); p += dpp_mov<0x141>(p); }

// one LSTM step; uses ambient W, hcv, la, lb, negK, gA, gB, c, hl, l, g, outp.
// sv = step index within window (parity: windows are 32 steps, so (sv+1)&1
// matches global parity). Advances outp by HID.
#define REC_STEP(sv, xnv, xnnv)                                               \
    {                                                                          \
        v2f pp0={0.f,0.f}, pp1={0.f,0.f}, pp2={0.f,0.f}, pp3={0.f,0.f};        \
        _Pragma("unroll")                                                      \
        for (int k = 0; k < 8; ++k) {                                          \
            pp0 = FMA2(W[0][k], hcv[k], pp0);                                  \
            pp1 = FMA2(W[1][k], hcv[k], pp1);                                  \
            pp2 = FMA2(W[2][k], hcv[k], pp2);                                  \
            pp3 = FMA2(W[3][k], hcv[k], pp3);                                  \
        }                                                                      \
        float p0 = pp0.x + pp0.y, p1 = pp1.x + pp1.y;                          \
        float p2 = pp2.x + pp2.y, p3 = pp3.x + pp3.y;                          \
        BF8(p0) BF8(p1) BF8(p2) BF8(p3)                                        \
        const float t01 = la ? p1 : p0;                                        \
        const float t23 = la ? p3 : p2;                                        \
        const float xv  = (lb ? t23 : t01) + (xnv);                            \
        const float e = __builtin_amdgcn_exp2f(xv * negK);                     \
        float r = __builtin_amdgcn_rcpf(1.f + e);                              \
        r = fmaf(r, gA, gB);                                                   \
        const float vi = dpp_mov<0x00>(r);                                     \
        const float vf = dpp_mov<0x55>(r);                                     \
        const float vg = dpp_mov<0xAA>(r);                                     \
        const float vo = dpp_mov<0xFF>(r);                                     \
        c = fmaf(vf, c, vi * vg);                                              \
        const float e2 = __builtin_amdgcn_exp2f(c * (-2.f * LOG2E));           \
        const float th = fmaf(2.f, __builtin_amdgcn_rcpf(1.f + e2), -1.f);     \
        const float h = vo * th;                                               \
        const int nb = ((sv) + 1) & 1;                                         \
        if (l == 0) {                                                          \
            hl[nb * 160 + 20 * (g >> 4) + (g & 15)] = h;                       \
            *outp = h;                                                         \
        }                                                                      \
        outp += HID;                                                           \
        __syncthreads();                                                       \
        _Pragma("unroll")                                                      \
        for (int k = 0; k < 4; ++k) {                                          \
            const v4f hv = *reinterpret_cast<const v4f*>(                      \
                &hl[nb * 160 + 20 * l + 4 * k]);                               \
            hcv[2*k] = hv.xy; hcv[2*k+1] = hv.zw;                              \
        }                                                                      \
        (xnv) = (xnnv);                                                        \
    }

// ---- shared xproj per-thread math: gate row j over 16 rows from LDS ----
__device__ __forceinline__ void xproj_rows16(const v4f* __restrict__ xrows,
                                             const float* __restrict__ W_ih,
                                             float bias, int j, float* __restrict__ acc) {
    const v4f* wr4 = reinterpret_cast<const v4f*>(W_ih + (size_t)j * HID);
    v2f wv[32];
    #pragma unroll
    for (int k = 0; k < 16; ++k) { const v4f t = wr4[k]; wv[2*k] = t.xy; wv[2*k+1] = t.zw; }
    #pragma unroll
    for (int k = 0; k < 32; ++k) PIN2(wv[k]);
    #pragma unroll
    for (int r = 0; r < 16; ++r) {                 // pass 0: k=0..63
        const v4f* xp = xrows + r * 32;
        v2f a0 = {0.f,0.f}, a1 = {0.f,0.f};
        #pragma unroll
        for (int k = 0; k < 16; ++k) {
            const v4f v = xp[k];
            a0 = FMA2(wv[2*k], v.xy, a0); a1 = FMA2(wv[2*k+1], v.zw, a1);
        }
        const v2f s = a0 + a1;
        acc[r] = bias + s.x + s.y;
    }
    #pragma unroll
    for (int k = 0; k < 16; ++k) { const v4f t = wr4[16+k]; wv[2*k] = t.xy; wv[2*k+1] = t.zw; }
    #pragma unroll
    for (int k = 0; k < 32; ++k) PIN2(wv[k]);
    #pragma unroll
    for (int r = 0; r < 16; ++r) {                 // pass 1: k=64..127
        const v4f* xp = xrows + r * 32 + 16;
        v2f a0 = {0.f,0.f}, a1 = {0.f,0.f};
        #pragma unroll
        for (int k = 0; k < 16; ++k) {
            const v4f v = xp[k];
            a0 = FMA2(wv[2*k], v.xy, a0); a1 = FMA2(wv[2*k+1], v.zw, a1);
        }
        const v2f s = a0 + a1;
        acc[r] += s.x + s.y;
    }
}

// ================= FUSED kernel =================
// xg ring: [b][w-1][s][gate], w=1..63 -> 252 MB.
__global__ __launch_bounds__(1024)
__attribute__((amdgpu_waves_per_eu(4, 4)))
void lstm_fused_kernel(const float* __restrict__ x, const float* __restrict__ h0,
                       const float* __restrict__ c0, const float* __restrict__ W_ih,
                       const float* __restrict__ W_hh, const float* __restrict__ b_ih,
                       const float* __restrict__ b_hh, float* __restrict__ out,
                       float* __restrict__ xg, int* __restrict__ flags) {
    __shared__ __align__(16) float lds_pool[24576];   // 96 KB -> 1 block/CU
    const int t = threadIdx.x;

    if (blockIdx.x >= BB) {
        // ---------- producer: window w = 1 + (tile>>6), batch bb ----------
        const int tile = blockIdx.x - BB;
        const int bb   = tile & 63;
        const int widx = tile >> 6;                // 0..62 -> window widx+1
        const int tc0  = (widx + 1) * 32;
        v4f* xs4 = reinterpret_cast<v4f*>(lds_pool);          // 16 KB
        const float* xsrc = x + ((size_t)bb * TT + tc0) * HID;
        xs4[t] = reinterpret_cast<const v4f*>(xsrc)[t];
        const int j  = t & 511;
        const int rg = t >> 9;
        const float bias = b_ih[j] + b_hh[j];
        __syncthreads();

        float acc[16];
        xproj_rows16(xs4 + rg * 16 * 32, W_ih, bias, j, acc);

        float* dst = xg + (((size_t)bb * 63 + widx) * 32 + rg * 16) * G4
                        + ((j & 127) << 2) + (j >> 7);
        #pragma unroll
        for (int r = 0; r < 16; ++r)
            dst[(size_t)r * G4] = acc[r];

        __syncthreads();
        if (t == 0)
            __hip_atomic_store(&flags[tile], 1, __ATOMIC_RELEASE,
                               __HIP_MEMORY_SCOPE_AGENT);
        return;
    }

    // ---------- consumer: recurrence chain b ----------
    const int g   = t >> 3;
    const int l   = t & 7;
    const int sel = l & 3;
    const int b   = blockIdx.x;
    float* hl  = lds_pool;                         // h_lds[2][160]  (320 f)
    float* xgl = lds_pool + 320;                   // window-0 xg [32][512]
    v4f*  xs4  = reinterpret_cast<v4f*>(lds_pool + 320 + 32 * G4);  // 16 KB

    // --- self-compute window 0 into LDS ---
    {
        const float* xsrc = x + (size_t)b * TT * HID;
        xs4[t] = reinterpret_cast<const v4f*>(xsrc)[t];       // rows 0..31
        const int j  = t & 511;
        const int rg = t >> 9;
        const float bias = b_ih[j] + b_hh[j];
        __syncthreads();
        float acc[16];
        xproj_rows16(xs4 + rg * 16 * 32, W_ih, bias, j, acc);
        float* dst = &xgl[(size_t)(rg * 16) * G4 + ((j & 127) << 2) + (j >> 7)];
        #pragma unroll
        for (int r = 0; r < 16; ++r)
            dst[(size_t)r * G4] = acc[r];
    }

    const float* wl = W_hh + 16 * l;
    v2f W[4][8];
    #pragma unroll
    for (int q = 0; q < 4; ++q) {
        const v4f* wp = reinterpret_cast<const v4f*>(wl + (size_t)(q * 128 + g) * HID);
        #pragma unroll
        for (int k = 0; k < 4; ++k) { const v4f tw = wp[k]; W[q][2*k] = tw.xy; W[q][2*k+1] = tw.zw; }
    }
    #pragma unroll
    for (int q = 0; q < 4; ++q)
        #pragma unroll
        for (int k = 0; k < 8; ++k) PIN2(W[q][k]);

    const bool  la   = (l & 1) != 0;
    const bool  lb   = (l & 2) != 0;
    const float negK = (sel == 2) ? -2.f * LOG2E : -LOG2E;
    const float gA   = (sel == 2) ? 2.f : 1.f;
    const float gB   = (sel == 2) ? -1.f : 0.f;

    float c = c0[b * HID + g];
    if (t < HID) {
        const int pi = 20 * (t >> 4) + (t & 15);
        hl[pi] = h0[b * HID + t];
    }
    __syncthreads();                               // xgl + h ready

    v2f hcv[8];
    #pragma unroll
    for (int k = 0; k < 4; ++k) {
        const v4f hv = *reinterpret_cast<const v4f*>(&hl[20 * l + 4 * k]);
        hcv[2*k] = hv.xy; hcv[2*k+1] = hv.zw;
    }

    const int off4 = 4 * g + sel;
    float* outp = out + (size_t)b * TT * HID + g;

    // --- window 0: tight LDS-only loop ---
    {
        const float* xw = xgl + off4;
        float xn = xw[0];
        #pragma unroll 1
        for (int s = 0; s < 32; ++s) {
            float xnn = 0.f;
            if (s + 1 < 32) xnn = xw[(size_t)(s + 1) * G4];
            REC_STEP(s, xn, xnn)
        }
    }

    // --- windows 1..63: tight global-only loops ---
    #pragma unroll 1
    for (int w = 1; w < 64; ++w) {
        const int fidx = (w - 1) * 64 + b;
        if (t == 0) {
            while (__hip_atomic_load(&flags[fidx], __ATOMIC_ACQUIRE,
                                     __HIP_MEMORY_SCOPE_AGENT) == 0)
                __builtin_amdgcn_s_sleep(8);
        }
        __syncthreads();
        const float* xw = xg + ((size_t)b * 63 + (w - 1)) * 32 * G4 + off4;
        float xn = xw[0];
        #pragma unroll 1
        for (int s = 0; s < 32; ++s) {
            float xnn = 0.f;
            if (s + 1 < 32) xnn = xw[(size_t)(s + 1) * G4];
            REC_STEP(s, xn, xnn)
        }
    }
}

// ================= fallback: chunked two-kernel path (R10) =================
__global__ __launch_bounds__(512)
__attribute__((amdgpu_waves_per_eu(4, 4)))
void xproj_kernel(const float* __restrict__ x, const float* __restrict__ W_ih,
                  const float* __restrict__ b_ih, const float* __restrict__ b_hh,
                  float* __restrict__ xg, int t0, int Tc) {
    __shared__ __align__(16) v4f xs4[16 * 32];
    const int j    = threadIdx.x;
    const int row0 = blockIdx.x * 16;
    const int b    = row0 / Tc;
    const int tc0  = row0 % Tc;
    const float* xsrc = x + ((size_t)b * TT + (size_t)t0 + tc0) * HID;
    xs4[j] = reinterpret_cast<const v4f*>(xsrc)[j];
    const float bias = b_ih[j] + b_hh[j];
    __syncthreads();
    float acc[16];
    xproj_rows16(xs4, W_ih, bias, j, acc);
    float* dst = xg + ((size_t)b * Tc + tc0) * G4 + ((j & 127) << 2) + (j >> 7);
    #pragma unroll
    for (int r = 0; r < 16; ++r)
        dst[(size_t)r * G4] = acc[r];
}

__global__ __launch_bounds__(1024)
__attribute__((amdgpu_waves_per_eu(4, 4)))
void lstm_rec_kernel(const float* __restrict__ xg, const float* __restrict__ h0,
                     const float* __restrict__ c0, const float* __restrict__ W_hh,
                     float* __restrict__ out, float* __restrict__ hstate,
                     float* __restrict__ cstate, int t0, int Tc) {
    __shared__ __align__(16) float h_lds_arr[2][160];
    float* hl = &h_lds_arr[0][0];
    const int t   = threadIdx.x;
    const int g   = t >> 3;
    const int l   = t & 7;
    const int sel = l & 3;
    const int b   = blockIdx.x;
    const float* wl = W_hh + 16 * l;
    v2f W[4][8];
    #pragma unroll
    for (int q = 0; q < 4; ++q) {
        const v4f* wp = reinterpret_cast<const v4f*>(wl + (size_t)(q * 128 + g) * HID);
        #pragma unroll
        for (int k = 0; k < 4; ++k) { const v4f tw = wp[k]; W[q][2*k] = tw.xy; W[q][2*k+1] = tw.zw; }
    }
    #pragma unroll
    for (int q = 0; q < 4; ++q)
        #pragma unroll
        for (int k = 0; k < 8; ++k) PIN2(W[q][k]);
    const bool  la   = (l & 1) != 0;
    const bool  lb   = (l & 2) != 0;
    const float negK = (sel == 2) ? -2.f * LOG2E : -LOG2E;
    const float gA   = (sel == 2) ? 2.f : 1.f;
    const float gB   = (sel == 2) ? -1.f : 0.f;
    float c = (t0 == 0) ? c0[b * HID + g] : cstate[b * HID + g];
    if (t < HID) {
        const int pi = 20 * (t >> 4) + (t & 15);
        hl[pi] = (t0 == 0) ? h0[b * HID + t] : hstate[b * HID + t];
    }
    __syncthreads();
    v2f hcv[8];
    #pragma unroll
    for (int k = 0; k < 4; ++k) {
        const v4f hv = *reinterpret_cast<const v4f*>(&hl[20 * l + 4 * k]);
        hcv[2*k] = hv.xy; hcv[2*k+1] = hv.zw;
    }
    const float* xq = xg + (size_t)b * Tc * G4 + 4 * g + sel;
    float* outp = out + ((size_t)b * TT + t0) * HID + g;
    float xn = xq[0];
    #pragma unroll 1
    for (int tc = 0; tc < Tc; ++tc) {
        float xnn = 0.f;
        if (tc + 1 < Tc) xnn = xq[(size_t)(tc + 1) * G4];
        REC_STEP(tc, xn, xnn)
    }
    if (l == 0) cstate[b * HID + g] = c;
    if (t < HID) {
        const int pi = 20 * (t >> 4) + (t & 15);
        hstate[b * HID + t] = hl[(Tc & 1) * 160 + pi];
    }
}

extern "C" void kernel_launch(void* const* d_in, const int* in_sizes, int n_in,
                              void* d_out, int out_size, void* d_ws, size_t ws_size,
                              hipStream_t stream) {
    const float* x    = (const float*)d_in[0];
    const float* h0   = (const float*)d_in[1];
    const float* c0   = (const float*)d_in[2];
    const float* W_ih = (const float*)d_in[3];
    const float* W_hh = (const float*)d_in[4];
    const float* b_ih = (const float*)d_in[5];
    const float* b_hh = (const float*)d_in[6];
    float* out = (float*)d_out;

    char*  ws = (char*)d_ws;
    float* xg = (float*)(ws + 65536);
    const size_t xg_ring = (size_t)BB * 63 * 32 * G4 * sizeof(float);  // 252 MB

    if (ws_size >= 65536 + xg_ring) {
        int* flags = (int*)ws;
        hipMemsetAsync(flags, 0, 16384, stream);
        lstm_fused_kernel<<<dim3(BB + 63 * 64), dim3(1024), 0, stream>>>(
            x, h0, c0, W_ih, W_hh, b_ih, b_hh, out, xg, flags);
        return;
    }

    // fallback: chunked sequential (R10)
    float* hstate = (float*)ws;
    float* cstate = (float*)(ws + 32768);
    const size_t per_t = (size_t)BB * G4 * sizeof(float);
    size_t avail = ws_size > 65536 ? ws_size - 65536 : 0;
    long long tc_ll = (long long)(avail / per_t);
    int Tc = tc_ll > TT ? TT : (int)tc_ll;
    Tc = (Tc / 64) * 64;
    if (Tc < 64) Tc = 64;
    for (int t0 = 0; t0 < TT; t0 += Tc) {
        const int Tcur = (TT - t0 < Tc) ? (TT - t0) : Tc;
        xproj_kernel<<<dim3(4 * Tcur), dim3(512), 0, stream>>>(x, W_ih, b_ih, b_hh,
                                                               xg, t0, Tcur);
        lstm_rec_kernel<<<dim3(BB), dim3(1024), 0, stream>>>(xg, h0, c0, W_hh, out,
                                                             hstate, cstate, t0, Tcur);
    }
}

// Round 15
// 1430.944 us; speedup vs baseline: 1.2340x; 1.2340x over previous
//
#include <hip/hip_runtime.h>
#include <cstdint>
#include <cmath>

// LSTM: B=64, T=2048, H=128, gates=4H=512. f32 throughout.
//
// Round 15: R14 showed the fused consumer stalls ~540cy/step on xg loads:
// ring+x+out (380MB) > L3 (256MB), so xg reads are HBM (~900-1100cy) and the
// 1-step prefetch slack (~1 step) is marginal; per-window acquire-invalidation
// makes window starts cold. Fix:
//   - depth-4 rotating register prefetch (xb0..xb3, static names): slack = 4
//     steps (~5800cy) >> HBM latency.
//   - window tail handoff: at s=28 current window is fully in registers ->
//     acquire flag(w+1) + issue its first 4 loads under the last 4 steps.
//   - nontemporal hints on touch-once traffic (producer x loads, consumer out
//     stores) to keep L3 for the xg ring.
// Protocol unchanged (R13/R14): producers cover windows 1..63 (252MB ring);
// consumer self-computes window 0 into LDS; release/acquire AGENT flags.

#define HID 128
#define G4  512
#define BB  64
#define TT  2048

typedef float v2f __attribute__((ext_vector_type(2)));
typedef float v4f __attribute__((ext_vector_type(4)));

#define PIN2(v) asm volatile("" : "+v"(v))
#define FMA2(A, B, C) __builtin_elementwise_fma((A), (B), (C))
#define LOG2E  1.442695041f

template<int CTRL>
__device__ __forceinline__ float dpp_mov(float v) {
    return __int_as_float(__builtin_amdgcn_update_dpp(
        0, __float_as_int(v), CTRL, 0xF, 0xF, true));
}
// 8-lane butterfly sum (validated R5-R10).
#define BF8(p) { p += dpp_mov<0xB1>(p); p += dpp_mov<0x4E>(p); p += dpp_mov<0x141>(p); }

// one LSTM step; ambient: W, hcv, la, lb, negK, gA, gB, c, hl, l, g, outp.
// nb parity only needs write==read consistency within the step (single
// barrier between write and re-read), so any per-step alternation works.
#define REC_STEP(sv, xval)                                                    \
    {                                                                          \
        v2f pp0={0.f,0.f}, pp1={0.f,0.f}, pp2={0.f,0.f}, pp3={0.f,0.f};        \
        _Pragma("unroll")                                                      \
        for (int k = 0; k < 8; ++k) {                                          \
            pp0 = FMA2(W[0][k], hcv[k], pp0);                                  \
            pp1 = FMA2(W[1][k], hcv[k], pp1);                                  \
            pp2 = FMA2(W[2][k], hcv[k], pp2);                                  \
            pp3 = FMA2(W[3][k], hcv[k], pp3);                                  \
        }                                                                      \
        float p0 = pp0.x + pp0.y, p1 = pp1.x + pp1.y;                          \
        float p2 = pp2.x + pp2.y, p3 = pp3.x + pp3.y;                          \
        BF8(p0) BF8(p1) BF8(p2) BF8(p3)                                        \
        const float t01_ = la ? p1 : p0;                                       \
        const float t23_ = la ? p3 : p2;                                       \
        const float xv_  = (lb ? t23_ : t01_) + (xval);                        \
        const float e_ = __builtin_amdgcn_exp2f(xv_ * negK);                   \
        float r_ = __builtin_amdgcn_rcpf(1.f + e_);                            \
        r_ = fmaf(r_, gA, gB);                                                 \
        const float vi_ = dpp_mov<0x00>(r_);                                   \
        const float vf_ = dpp_mov<0x55>(r_);                                   \
        const float vg_ = dpp_mov<0xAA>(r_);                                   \
        const float vo_ = dpp_mov<0xFF>(r_);                                   \
        c = fmaf(vf_, c, vi_ * vg_);                                           \
        const float e2_ = __builtin_amdgcn_exp2f(c * (-2.f * LOG2E));          \
        const float th_ = fmaf(2.f, __builtin_amdgcn_rcpf(1.f + e2_), -1.f);   \
        const float h_ = vo_ * th_;                                            \
        const int nb_ = ((sv) + 1) & 1;                                        \
        if (l == 0) {                                                          \
            hl[nb_ * 160 + 20 * (g >> 4) + (g & 15)] = h_;                     \
            __builtin_nontemporal_store(h_, outp);                             \
        }                                                                      \
        outp += HID;                                                           \
        __syncthreads();                                                       \
        _Pragma("unroll")                                                      \
        for (int k = 0; k < 4; ++k) {                                          \
            const v4f hv_ = *reinterpret_cast<const v4f*>(                     \
                &hl[nb_ * 160 + 20 * l + 4 * k]);                              \
            hcv[2*k] = hv_.xy; hcv[2*k+1] = hv_.zw;                            \
        }                                                                      \
    }

#define WAITFLAG(idx)                                                         \
    { if (t == 0) {                                                            \
        while (__hip_atomic_load(&flags[idx], __ATOMIC_ACQUIRE,                \
                                 __HIP_MEMORY_SCOPE_AGENT) == 0)               \
            __builtin_amdgcn_s_sleep(8); }                                     \
      __syncthreads(); }

// ---- shared xproj per-thread math: gate row j over 16 rows from LDS ----
__device__ __forceinline__ void xproj_rows16(const v4f* __restrict__ xrows,
                                             const float* __restrict__ W_ih,
                                             float bias, int j, float* __restrict__ acc) {
    const v4f* wr4 = reinterpret_cast<const v4f*>(W_ih + (size_t)j * HID);
    v2f wv[32];
    #pragma unroll
    for (int k = 0; k < 16; ++k) { const v4f t = wr4[k]; wv[2*k] = t.xy; wv[2*k+1] = t.zw; }
    #pragma unroll
    for (int k = 0; k < 32; ++k) PIN2(wv[k]);
    #pragma unroll
    for (int r = 0; r < 16; ++r) {                 // pass 0: k=0..63
        const v4f* xp = xrows + r * 32;
        v2f a0 = {0.f,0.f}, a1 = {0.f,0.f};
        #pragma unroll
        for (int k = 0; k < 16; ++k) {
            const v4f v = xp[k];
            a0 = FMA2(wv[2*k], v.xy, a0); a1 = FMA2(wv[2*k+1], v.zw, a1);
        }
        const v2f s = a0 + a1;
        acc[r] = bias + s.x + s.y;
    }
    #pragma unroll
    for (int k = 0; k < 16; ++k) { const v4f t = wr4[16+k]; wv[2*k] = t.xy; wv[2*k+1] = t.zw; }
    #pragma unroll
    for (int k = 0; k < 32; ++k) PIN2(wv[k]);
    #pragma unroll
    for (int r = 0; r < 16; ++r) {                 // pass 1: k=64..127
        const v4f* xp = xrows + r * 32 + 16;
        v2f a0 = {0.f,0.f}, a1 = {0.f,0.f};
        #pragma unroll
        for (int k = 0; k < 16; ++k) {
            const v4f v = xp[k];
            a0 = FMA2(wv[2*k], v.xy, a0); a1 = FMA2(wv[2*k+1], v.zw, a1);
        }
        const v2f s = a0 + a1;
        acc[r] += s.x + s.y;
    }
}

// ================= FUSED kernel =================
// xg ring: [b][w-1][s][gate], w=1..63 -> 252 MB (contiguous in w per b).
__global__ __launch_bounds__(1024)
__attribute__((amdgpu_waves_per_eu(4, 4)))
void lstm_fused_kernel(const float* __restrict__ x, const float* __restrict__ h0,
                       const float* __restrict__ c0, const float* __restrict__ W_ih,
                       const float* __restrict__ W_hh, const float* __restrict__ b_ih,
                       const float* __restrict__ b_hh, float* __restrict__ out,
                       float* __restrict__ xg, int* __restrict__ flags) {
    __shared__ __align__(16) float lds_pool[24576];   // 96 KB -> 1 block/CU
    const int t = threadIdx.x;

    if (blockIdx.x >= BB) {
        // ---------- producer: window w = 1 + (tile>>6), batch bb ----------
        const int tile = blockIdx.x - BB;
        const int bb   = tile & 63;
        const int widx = tile >> 6;                // 0..62 -> window widx+1
        const int tc0  = (widx + 1) * 32;
        v4f* xs4 = reinterpret_cast<v4f*>(lds_pool);          // 16 KB
        const float* xsrc = x + ((size_t)bb * TT + tc0) * HID;
        xs4[t] = __builtin_nontemporal_load(
                     reinterpret_cast<const v4f*>(xsrc) + t);  // touch-once
        const int j  = t & 511;
        const int rg = t >> 9;
        const float bias = b_ih[j] + b_hh[j];
        __syncthreads();

        float acc[16];
        xproj_rows16(xs4 + rg * 16 * 32, W_ih, bias, j, acc);

        float* dst = xg + (((size_t)bb * 63 + widx) * 32 + rg * 16) * G4
                        + ((j & 127) << 2) + (j >> 7);
        #pragma unroll
        for (int r = 0; r < 16; ++r)
            dst[(size_t)r * G4] = acc[r];

        __syncthreads();
        if (t == 0)
            __hip_atomic_store(&flags[tile], 1, __ATOMIC_RELEASE,
                               __HIP_MEMORY_SCOPE_AGENT);
        return;
    }

    // ---------- consumer: recurrence chain b ----------
    const int g   = t >> 3;
    const int l   = t & 7;
    const int sel = l & 3;
    const int b   = blockIdx.x;
    float* hl  = lds_pool;                         // h_lds[2][160]  (320 f)
    float* xgl = lds_pool + 320;                   // window-0 xg [32][512]
    v4f*  xs4  = reinterpret_cast<v4f*>(lds_pool + 320 + 32 * G4);  // 16 KB

    // --- self-compute window 0 into LDS ---
    {
        const float* xsrc = x + (size_t)b * TT * HID;
        xs4[t] = __builtin_nontemporal_load(
                     reinterpret_cast<const v4f*>(xsrc) + t);  // rows 0..31
        const int j  = t & 511;
        const int rg = t >> 9;
        const float bias = b_ih[j] + b_hh[j];
        __syncthreads();
        float acc[16];
        xproj_rows16(xs4 + rg * 16 * 32, W_ih, bias, j, acc);
        float* dst = &xgl[(size_t)(rg * 16) * G4 + ((j & 127) << 2) + (j >> 7)];
        #pragma unroll
        for (int r = 0; r < 16; ++r)
            dst[(size_t)r * G4] = acc[r];
    }

    const float* wl = W_hh + 16 * l;
    v2f W[4][8];
    #pragma unroll
    for (int q = 0; q < 4; ++q) {
        const v4f* wp = reinterpret_cast<const v4f*>(wl + (size_t)(q * 128 + g) * HID);
        #pragma unroll
        for (int k = 0; k < 4; ++k) { const v4f tw = wp[k]; W[q][2*k] = tw.xy; W[q][2*k+1] = tw.zw; }
    }
    #pragma unroll
    for (int q = 0; q < 4; ++q)
        #pragma unroll
        for (int k = 0; k < 8; ++k) PIN2(W[q][k]);

    const bool  la   = (l & 1) != 0;
    const bool  lb   = (l & 2) != 0;
    const float negK = (sel == 2) ? -2.f * LOG2E : -LOG2E;
    const float gA   = (sel == 2) ? 2.f : 1.f;
    const float gB   = (sel == 2) ? -1.f : 0.f;

    float c = c0[b * HID + g];
    if (t < HID) {
        const int pi = 20 * (t >> 4) + (t & 15);
        hl[pi] = h0[b * HID + t];
    }
    __syncthreads();                               // xgl + h ready

    v2f hcv[8];
    #pragma unroll
    for (int k = 0; k < 4; ++k) {
        const v4f hv = *reinterpret_cast<const v4f*>(&hl[20 * l + 4 * k]);
        hcv[2*k] = hv.xy; hcv[2*k+1] = hv.zw;
    }

    const int off4 = 4 * g + sel;
    float* outp = out + (size_t)b * TT * HID + g;
    const float* ring = xg + (size_t)b * 63 * 32 * G4 + off4;  // window 1 base

    float xb0, xb1, xb2, xb3;                      // depth-4 prefetch regs

    // --- window 0: LDS-only; tail acquires window 1 + prefetches its head ---
    {
        const float* xw0 = xgl + off4;
        #pragma unroll 1
        for (int s = 0; s < 28; ++s) {
            const float xv0 = xw0[(size_t)s * G4];
            REC_STEP(s, xv0)
        }
        WAITFLAG(b)                                // window 1 ready
        xb0 = ring[0 * G4]; xb1 = ring[1 * G4];
        xb2 = ring[2 * G4]; xb3 = ring[3 * G4];
        #pragma unroll
        for (int s = 28; s < 32; ++s) {
            const float xv0 = xw0[(size_t)s * G4];
            REC_STEP(s, xv0)
        }
    }

    // --- windows 1..63: depth-4 rotating prefetch, tail handoff ---
    #pragma unroll 1
    for (int w = 1; w < 64; ++w) {
        const float* xw = ring + (size_t)(w - 1) * 32 * G4;
        #pragma unroll 1
        for (int s = 0; s < 24; s += 4) {          // steps 0..23
            REC_STEP(0, xb0)  xb0 = xw[(size_t)(s + 4) * G4];
            REC_STEP(1, xb1)  xb1 = xw[(size_t)(s + 5) * G4];
            REC_STEP(2, xb2)  xb2 = xw[(size_t)(s + 6) * G4];
            REC_STEP(3, xb3)  xb3 = xw[(size_t)(s + 7) * G4];
        }
        // steps 24..27: reload window tail (28..31)
        REC_STEP(0, xb0)  xb0 = xw[(size_t)28 * G4];
        REC_STEP(1, xb1)  xb1 = xw[(size_t)29 * G4];
        REC_STEP(2, xb2)  xb2 = xw[(size_t)30 * G4];
        REC_STEP(3, xb3)  xb3 = xw[(size_t)31 * G4];
        // steps 28..31: acquire next window, prefetch its head underneath
        if (w < 63) {
            WAITFLAG(w * 64 + b)
            const float* xwn = xw + (size_t)32 * G4;
            REC_STEP(0, xb0)  xb0 = xwn[0 * G4];
            REC_STEP(1, xb1)  xb1 = xwn[1 * G4];
            REC_STEP(2, xb2)  xb2 = xwn[2 * G4];
            REC_STEP(3, xb3)  xb3 = xwn[3 * G4];
        } else {
            REC_STEP(0, xb0) REC_STEP(1, xb1) REC_STEP(2, xb2) REC_STEP(3, xb3)
        }
    }
}

// ================= fallback: chunked two-kernel path =================
__global__ __launch_bounds__(512)
__attribute__((amdgpu_waves_per_eu(4, 4)))
void xproj_kernel(const float* __restrict__ x, const float* __restrict__ W_ih,
                  const float* __restrict__ b_ih, const float* __restrict__ b_hh,
                  float* __restrict__ xg, int t0, int Tc) {
    __shared__ __align__(16) v4f xs4[16 * 32];
    const int j    = threadIdx.x;
    const int row0 = blockIdx.x * 16;
    const int b    = row0 / Tc;
    const int tc0  = row0 % Tc;
    const float* xsrc = x + ((size_t)b * TT + (size_t)t0 + tc0) * HID;
    xs4[j] = reinterpret_cast<const v4f*>(xsrc)[j];
    const float bias = b_ih[j] + b_hh[j];
    __syncthreads();
    float acc[16];
    xproj_rows16(xs4, W_ih, bias, j, acc);
    float* dst = xg + ((size_t)b * Tc + tc0) * G4 + ((j & 127) << 2) + (j >> 7);
    #pragma unroll
    for (int r = 0; r < 16; ++r)
        dst[(size_t)r * G4] = acc[r];
}

__global__ __launch_bounds__(1024)
__attribute__((amdgpu_waves_per_eu(4, 4)))
void lstm_rec_kernel(const float* __restrict__ xg, const float* __restrict__ h0,
                     const float* __restrict__ c0, const float* __restrict__ W_hh,
                     float* __restrict__ out, float* __restrict__ hstate,
                     float* __restrict__ cstate, int t0, int Tc) {
    __shared__ __align__(16) float h_lds_arr[2][160];
    float* hl = &h_lds_arr[0][0];
    const int t   = threadIdx.x;
    const int g   = t >> 3;
    const int l   = t & 7;
    const int sel = l & 3;
    const int b   = blockIdx.x;
    const float* wl = W_hh + 16 * l;
    v2f W[4][8];
    #pragma unroll
    for (int q = 0; q < 4; ++q) {
        const v4f* wp = reinterpret_cast<const v4f*>(wl + (size_t)(q * 128 + g) * HID);
        #pragma unroll
        for (int k = 0; k < 4; ++k) { const v4f tw = wp[k]; W[q][2*k] = tw.xy; W[q][2*k+1] = tw.zw; }
    }
    #pragma unroll
    for (int q = 0; q < 4; ++q)
        #pragma unroll
        for (int k = 0; k < 8; ++k) PIN2(W[q][k]);
    const bool  la   = (l & 1) != 0;
    const bool  lb   = (l & 2) != 0;
    const float negK = (sel == 2) ? -2.f * LOG2E : -LOG2E;
    const float gA   = (sel == 2) ? 2.f : 1.f;
    const float gB   = (sel == 2) ? -1.f : 0.f;
    float c = (t0 == 0) ? c0[b * HID + g] : cstate[b * HID + g];
    if (t < HID) {
        const int pi = 20 * (t >> 4) + (t & 15);
        hl[pi] = (t0 == 0) ? h0[b * HID + t] : hstate[b * HID + t];
    }
    __syncthreads();
    v2f hcv[8];
    #pragma unroll
    for (int k = 0; k < 4; ++k) {
        const v4f hv = *reinterpret_cast<const v4f*>(&hl[20 * l + 4 * k]);
        hcv[2*k] = hv.xy; hcv[2*k+1] = hv.zw;
    }
    const float* xq = xg + (size_t)b * Tc * G4 + 4 * g + sel;
    float* outp = out + ((size_t)b * TT + t0) * HID + g;
    float xn = xq[0];
    #pragma unroll 1
    for (int tc = 0; tc < Tc; ++tc) {
        const float xv0 = xn;
        if (tc + 1 < Tc) xn = xq[(size_t)(tc + 1) * G4];
        REC_STEP(tc, xv0)
    }
    if (l == 0) cstate[b * HID + g] = c;
    if (t < HID) {
        const int pi = 20 * (t >> 4) + (t & 15);
        hstate[b * HID + t] = hl[(Tc & 1) * 160 + pi];
    }
}

extern "C" void kernel_launch(void* const* d_in, const int* in_sizes, int n_in,
                              void* d_out, int out_size, void* d_ws, size_t ws_size,
                              hipStream_t stream) {
    const float* x    = (const float*)d_in[0];
    const float* h0   = (const float*)d_in[1];
    const float* c0   = (const float*)d_in[2];
    const float* W_ih = (const float*)d_in[3];
    const float* W_hh = (const float*)d_in[4];
    const float* b_ih = (const float*)d_in[5];
    const float* b_hh = (const float*)d_in[6];
    float* out = (float*)d_out;

    char*  ws = (char*)d_ws;
    float* xg = (float*)(ws + 65536);
    const size_t xg_ring = (size_t)BB * 63 * 32 * G4 * sizeof(float);  // 252 MB

    if (ws_size >= 65536 + xg_ring) {
        int* flags = (int*)ws;
        hipMemsetAsync(flags, 0, 16384, stream);
        lstm_fused_kernel<<<dim3(BB + 63 * 64), dim3(1024), 0, stream>>>(
            x, h0, c0, W_ih, W_hh, b_ih, b_hh, out, xg, flags);
        return;
    }

    // fallback: chunked sequential
    float* hstate = (float*)ws;
    float* cstate = (float*)(ws + 32768);
    const size_t per_t = (size_t)BB * G4 * sizeof(float);
    size_t avail = ws_size > 65536 ? ws_size - 65536 : 0;
    long long tc_ll = (long long)(avail / per_t);
    int Tc = tc_ll > TT ? TT : (int)tc_ll;
    Tc = (Tc / 64) * 64;
    if (Tc < 64) Tc = 64;
    for (int t0 = 0; t0 < TT; t0 += Tc) {
        const int Tcur = (TT - t0 < Tc) ? (TT - t0) : Tc;
        xproj_kernel<<<dim3(4 * Tcur), dim3(512), 0, stream>>>(x, W_ih, b_ih, b_hh,
                                                               xg, t0, Tcur);
        lstm_rec_kernel<<<dim3(BB), dim3(1024), 0, stream>>>(xg, h0, c0, W_hh, out,
                                                             hstate, cstate, t0, Tcur);
    }
}